// Round 12
// baseline (15385.786 us; speedup 1.0000x reference)
//
#include <hip/hip_runtime.h>
#include <hip/hip_bf16.h>

// LSTM seq2seq: B=256, T=256 enc + 256 dec, D_IN=512, HID=OUT=1024.
// Base = round-10 kernel (PASSED, 10.6ms): persistent 256 WGs (1/CU),
// fence-free hierarchical grid barrier, sc1/LLC-coherent cross-WG data,
// L2-resident weights, 3-pass split-bf16 MFMA.
// vs r11 (failed): two pipeline bugs fixed.
//  (1) prologue now issues aload(4) -- r11 never loaded chunk 4, so body(3)
//      ds-wrote chunk-0 data as chunk 4 (the 0.24 absmax).
//  (2) vmcnt ladder re-derived op-by-op for the corrected issue schedule:
//      prologue 36; c=0 -> 16, c=1 -> 24; steady 32; tail 24/16/4/0.
//      Each wait retires exactly {stageB(c), aload(c+1)} before the barrier.

#define NB   256
#define TSEQ 256
#define DIN  512
#define HID  1024
#define G4   4096

typedef __attribute__((ext_vector_type(8))) __bf16 bf16x8;
typedef __attribute__((ext_vector_type(4))) float  f32x4;
typedef unsigned long long ull;

struct alignas(16) ull2 { ull a, b; };

static __device__ __forceinline__ unsigned short f2bf(float v) {
    unsigned u; __builtin_memcpy(&u, &v, 4);
    return (unsigned short)((u + 0x7FFFu + ((u >> 16) & 1u)) >> 16);  // RNE
}
static __device__ __forceinline__ float bf2f(unsigned short b) {
    unsigned u = ((unsigned)b) << 16; float f; __builtin_memcpy(&f, &u, 4); return f;
}
static __device__ __forceinline__ float fsig(float x) {
    return 1.f / (1.f + __expf(-x));
}
static __device__ __forceinline__ float ftanh(float x) {
    return 2.f / (1.f + __expf(-2.f * x)) - 1.f;   // safe at |x| large
}
static __device__ __forceinline__ void glds16(const void* g, void* l) {
    __builtin_amdgcn_global_load_lds(
        (const __attribute__((address_space(1))) unsigned int*)g,
        (__attribute__((address_space(3))) unsigned int*)l, 16, 0, 0);
}
// Agent-scope (LLC-commit) stores for cross-WG data (r10-proven).
static __device__ __forceinline__ void st16_ag(unsigned short* p, unsigned short v) {
    asm volatile("global_store_short %0, %1, off sc1"
                 :: "v"(p), "v"((unsigned)v) : "memory");
}
static __device__ __forceinline__ void st32_ag(unsigned* p, unsigned v) {
    asm volatile("global_store_dword %0, %1, off sc1"
                 :: "v"(p), "v"(v) : "memory");
}

// W [K][N] f32 -> T_hi/T_lo [N][K] bf16 split (transposed)
__global__ __launch_bounds__(256) void split_transpose(
        const float* __restrict__ W, unsigned short* __restrict__ T_hi,
        unsigned short* __restrict__ T_lo, int K, int N) {
    __shared__ float tile[64][65];
    const int kb = blockIdx.x * 64, nb = blockIdx.y * 64;
    const int tid = threadIdx.x;
    const int r = tid >> 2, c0 = (tid & 3) << 4;
    #pragma unroll
    for (int j = 0; j < 16; j += 4) {
        float4 v = *(const float4*)(W + (size_t)(kb + r) * N + nb + c0 + j);
        tile[r][c0 + j + 0] = v.x; tile[r][c0 + j + 1] = v.y;
        tile[r][c0 + j + 2] = v.z; tile[r][c0 + j + 3] = v.w;
    }
    __syncthreads();
    #pragma unroll
    for (int j = 0; j < 16; ++j) {
        float v = tile[c0 + j][r];
        unsigned short hi = f2bf(v);
        unsigned short lo = f2bf(v - bf2f(hi));
        size_t o = (size_t)(nb + r) * K + kb + c0 + j;
        T_hi[o] = hi; T_lo[o] = lo;
    }
}

// LDS layout (113 KB total):
//   A bufs: 2 x 16KB @ 0        (hi 8K | lo 8K), chunk c -> buf c&1
//   B bufs: 4 x 16KB @ 32768    (hi 8K | lo 8K), chunk c -> buf c&3
//   sG separate.
// Tile layout per 8K region: [64 rows][8 segs of 16B], slot(m,s) at
// byte m*128 + ((s ^ (m&7))*16)  (same swizzle as r6-r10, HW-proven).
__global__ __launch_bounds__(256, 1) void lstm_persist(
        const float* __restrict__ x,
        const unsigned short* __restrict__ encT_hi, const unsigned short* __restrict__ encT_lo,
        const unsigned short* __restrict__ decT_hi, const unsigned short* __restrict__ decT_lo,
        const unsigned short* __restrict__ WhT_hi, const unsigned short* __restrict__ WhT_lo,
        const unsigned short* __restrict__ WcT_hi, const unsigned short* __restrict__ WcT_lo,
        const float* __restrict__ enc_b, const float* __restrict__ dec_b,
        const float* __restrict__ bhv, const float* __restrict__ bcv,
        unsigned short* h_hi0, unsigned short* h_lo0,
        unsigned short* h_hi1, unsigned short* h_lo1,
        unsigned short* ce_hi, unsigned short* ce_lo,
        float* c0, float* c1,
        unsigned short* x_hi0, unsigned short* x_lo0,
        unsigned short* x_hi1, unsigned short* x_lo1,
        unsigned* barcnt, float* __restrict__ out) {
    __shared__ __align__(16) char smem[98304];
    __shared__ float sG[64][68];
    const int wg   = blockIdx.x;
    const int row0 = (wg >> 6) << 6;   // 4 m-blocks of 64 rows
    const int hc0  = (wg & 63) << 4;   // 64 n-groups of 16 h-cols; wg%8 pins XCD
    const int tid  = threadIdx.x;
    const int lane = tid & 63;
    const int wv   = tid >> 6;
    const int rA   = (wv >> 1) << 5;
    const int cB   = (wv & 1) << 5;
    const int n    = tid & 15, mq = tid >> 4;

    // ---- hierarchical grid barrier, fence-free (r10-proven) ----
    unsigned bar_e = 0;
    auto gbar = [&]() {
        __syncthreads();                       // drains vmem: sc1 stores committed
        ++bar_e;
        if (tid == 0) {
            __hip_atomic_fetch_add(barcnt + ((wg & 7) << 5), 1u,
                                   __ATOMIC_RELAXED, __HIP_MEMORY_SCOPE_AGENT);
            if (wg == 0) {
                const unsigned target = bar_e << 8;       // 256 * epoch
                for (;;) {
                    unsigned s = 0;
                    #pragma unroll
                    for (int i = 0; i < 8; ++i)
                        s += __hip_atomic_load(barcnt + (i << 5),
                                               __ATOMIC_RELAXED, __HIP_MEMORY_SCOPE_AGENT);
                    if (s >= target) break;
                    __builtin_amdgcn_s_sleep(1);
                }
                __hip_atomic_fetch_add(barcnt + 256, 1u,
                                       __ATOMIC_RELAXED, __HIP_MEMORY_SCOPE_AGENT);
            } else {
                while (__hip_atomic_load(barcnt + 256,
                                         __ATOMIC_RELAXED, __HIP_MEMORY_SCOPE_AGENT) < bar_e)
                    __builtin_amdgcn_s_sleep(2);
            }
        }
        __syncthreads();
    };

    // ---- phase descriptors ----
    const unsigned short *g_Axh = nullptr, *g_Axl = nullptr;   // x-type A (stride DIN)
    const unsigned short *g_Ahh = nullptr, *g_Ahl = nullptr;   // h-type A (stride HID)
    const unsigned short *g_Bh = nullptr, *g_Bl = nullptr;
    int g_sb = 0, g_kb0 = 0, g_nx = 0, g_colw0 = 0, g_arow0 = 0;

    // B staging: 4 glds/thread per chunk (plain: weights L2-resident).
    auto stageB = [&](int c, int buf) {
        char* bb = smem + 32768 + buf * 16384;
        const int k0b = g_kb0 + (c << 6);
        const int kseg = (lane & 7) ^ ((lane >> 3) & 7);
        #pragma unroll
        for (int j = 0; j < 2; ++j) {
            const int colw = g_colw0 + (j << 3) + (lane >> 3);
            const size_t go = (size_t)colw * g_sb + k0b + (kseg << 3);
            const int gclb = (wv << 4) + (j << 3);
            glds16(g_Bh + go, bb + (gclb << 7));
            glds16(g_Bl + go, bb + 8192 + (gclb << 7));
        }
    };

    // A staging: 8 agent atomic u64 loads/thread per chunk (sc1, cross-WG).
    // Thread (mA = tid>>2, qa = tid&3) owns row mA, k = 16*qa..16*qa+15.
    auto aload = [&](int ch, ull (&r)[8]) {
        const unsigned short *Ah, *Al; int sa, ka;
        if (ch < g_nx) { Ah = g_Axh; Al = g_Axl; sa = DIN; ka = ch << 6; }
        else           { Ah = g_Ahh; Al = g_Ahl; sa = HID; ka = (ch - g_nx) << 6; }
        const int qa = tid & 3, mA = tid >> 2;
        const ull* ph = (const ull*)(Ah + (size_t)(g_arow0 + mA) * sa + ka + (qa << 4));
        const ull* pl = (const ull*)(Al + (size_t)(g_arow0 + mA) * sa + ka + (qa << 4));
        #pragma unroll
        for (int i = 0; i < 4; ++i)
            r[i] = __hip_atomic_load(ph + i, __ATOMIC_RELAXED, __HIP_MEMORY_SCOPE_AGENT);
        #pragma unroll
        for (int i = 0; i < 4; ++i)
            r[4 + i] = __hip_atomic_load(pl + i, __ATOMIC_RELAXED, __HIP_MEMORY_SCOPE_AGENT);
    };
    // regs -> LDS A-buf (ch&1), same swizzled slot layout the glds path used.
    auto dswrite = [&](int ch, const ull (&r)[8]) {
        char* ab = smem + (ch & 1) * 16384;
        const int qa = tid & 3, mA = tid >> 2;
        const int base = mA << 7, sw = mA & 7;
        const int o0 = base + ((((qa << 1) + 0) ^ sw) << 4);
        const int o1 = base + ((((qa << 1) + 1) ^ sw) << 4);
        *(ull2*)(ab + o0)        = ull2{r[0], r[1]};
        *(ull2*)(ab + o1)        = ull2{r[2], r[3]};
        *(ull2*)(ab + 8192 + o0) = ull2{r[4], r[5]};
        *(ull2*)(ab + 8192 + o1) = ull2{r[6], r[7]};
    };

    auto compute = [&](int c, f32x4 (&acc)[2][2]) {
        const char* ab  = smem + (c & 1) * 16384;
        const char* bbf = smem + 32768 + (c & 3) * 16384;
        const char* sah = ab;
        const char* sal = ab + 8192;
        const char* sbh = bbf;
        const char* sbl = bbf + 8192;
        #pragma unroll
        for (int kk = 0; kk < 2; ++kk) {
            const int kb = (kk << 6) | ((lane >> 4) << 4);
            bf16x8 ah[2], al[2], bh[2], bl[2];
            #pragma unroll
            for (int ms = 0; ms < 2; ++ms) {
                const int m  = rA + (ms << 4) + (lane & 15);
                const int ad = (m << 7) + (kb ^ ((m & 7) << 4));
                ah[ms] = *(const bf16x8*)(sah + ad);
                al[ms] = *(const bf16x8*)(sal + ad);
            }
            #pragma unroll
            for (int ns = 0; ns < 2; ++ns) {
                const int gcl = cB + (ns << 4) + (lane & 15);
                const int ad  = (gcl << 7) + (kb ^ ((gcl & 7) << 4));
                bh[ns] = *(const bf16x8*)(sbh + ad);
                bl[ns] = *(const bf16x8*)(sbl + ad);
            }
            #pragma unroll
            for (int ms = 0; ms < 2; ++ms)
                #pragma unroll
                for (int ns = 0; ns < 2; ++ns) {
                    acc[ms][ns] = __builtin_amdgcn_mfma_f32_16x16x32_bf16(ah[ms], bh[ns], acc[ms][ns], 0, 0, 0);
                    acc[ms][ns] = __builtin_amdgcn_mfma_f32_16x16x32_bf16(al[ms], bh[ns], acc[ms][ns], 0, 0, 0);
                    acc[ms][ns] = __builtin_amdgcn_mfma_f32_16x16x32_bf16(ah[ms], bl[ns], acc[ms][ns], 0, 0, 0);
                }
        }
    };

    auto vwait = [&](int nw) {
        if (nw >= 32)      asm volatile("s_waitcnt vmcnt(32)" ::: "memory");
        else if (nw == 24) asm volatile("s_waitcnt vmcnt(24)" ::: "memory");
        else if (nw == 16) asm volatile("s_waitcnt vmcnt(16)" ::: "memory");
        else if (nw == 4)  asm volatile("s_waitcnt vmcnt(4)"  ::: "memory");
        else               asm volatile("s_waitcnt vmcnt(0)"  ::: "memory");
    };

    // Body c: wait {stageB(c) in LDS, aload(c+1) in regs}; barrier;
    // dswrite(c+1); issue B(c+3), A(c+5) (post-barrier: straggler-race-free);
    // compute(c). sw = reg-set (c+1)&3.
    // Ladder (derived op-by-op for the issue schedule below):
    //   c=0 -> 16, c=1 -> 24, steady 32; tail rem=3 ->24, rem=2 ->16,
    //   rem=1 -> 4, rem=0 -> 0.  Each wait retires {B(c), a(c+1)} exactly.
    auto body = [&](int c, int nch, ull (&sw)[8], f32x4 (&acc)[2][2]) {
        int nw;
        if (c == 0) nw = 16;
        else if (c == 1) nw = 24;
        else {
            const int rem = nch - 1 - c;
            nw = (rem >= 4) ? 32 : (rem == 3) ? 24 : (rem == 2) ? 16 : (rem == 1) ? 4 : 0;
        }
        vwait(nw);
        asm volatile("s_waitcnt lgkmcnt(0)" ::: "memory");
        __builtin_amdgcn_s_barrier();
        if (c + 1 < nch) dswrite(c + 1, sw);
        if (c + 3 < nch) stageB(c + 3, (c + 3) & 3);
        if (c + 5 < nch) aload(c + 5, sw);
        compute(c, acc);
    };

    auto run_chunks = [&](int nch, f32x4 (&acc)[2][2]) {
        ull r0[8], r1[8], r2[8], r3[8];
        // prologue: a0 a1 a2 a3 B0 B1 B2 (44 ops) | wait a0 | dsw(0) | a4.
        aload(0, r0); aload(1, r1); aload(2, r2); aload(3, r3);
        stageB(0, 0); stageB(1, 1); stageB(2, 2);
        asm volatile("s_waitcnt vmcnt(36)" ::: "memory");
        dswrite(0, r0);
        aload(4, r0);                  // r11 BUG FIX: chunk 4 was never loaded
        for (int cb = 0; cb < nch; cb += 4) {      // nch % 4 == 0 always
            body(cb + 0, nch, r1, acc);
            body(cb + 1, nch, r2, acc);
            body(cb + 2, nch, r3, acc);
            body(cb + 3, nch, r0, acc);
        }
    };

    auto acc2sG = [&](f32x4 (&acc)[2][2]) {
        #pragma unroll
        for (int ms = 0; ms < 2; ++ms)
            #pragma unroll
            for (int ns = 0; ns < 2; ++ns)
                #pragma unroll
                for (int r = 0; r < 4; ++r)
                    sG[cB + (ns << 4) + (lane & 15)]
                      [rA + (ms << 4) + ((lane >> 4) << 2) + r] = acc[ms][ns][r];
    };

    // x[tn] -> bf16 hi/lo split, one step ahead (sc1 stores: read cross-WG)
    auto convert = [&](int tn) {
        unsigned short* xh = (tn & 1) ? x_hi1 : x_hi0;
        unsigned short* xl = (tn & 1) ? x_lo1 : x_lo0;
        const int r = tid & 63, cp = tid >> 6;
        const int row = row0 + r;
        const int col = ((wg & 63) << 3) + (cp << 1);
        const ull pv = __builtin_nontemporal_load(
            (const ull*)(x + ((size_t)row * TSEQ + tn) * DIN + col));
        const float fx = __uint_as_float((unsigned)pv);
        const float fy = __uint_as_float((unsigned)(pv >> 32));
        const unsigned short hx = f2bf(fx), lx = f2bf(fx - bf2f(hx));
        const unsigned short hy = f2bf(fy), ly = f2bf(fy - bf2f(hy));
        st32_ag((unsigned*)(xh + (size_t)row * DIN + col), (unsigned)hx | ((unsigned)hy << 16));
        st32_ag((unsigned*)(xl + (size_t)row * DIN + col), (unsigned)lx | ((unsigned)ly << 16));
    };

    // encoder bias (per-thread constants)
    const float be0 = enc_b[hc0 + n];
    const float be1 = enc_b[HID + hc0 + n];
    const float be2 = enc_b[2 * HID + hc0 + n];
    const float be3 = enc_b[3 * HID + hc0 + n];

    // ================= encoder: 256 steps =================
    g_Bh = encT_hi; g_Bl = encT_lo; g_sb = 1536; g_kb0 = 0; g_nx = 8;
    g_colw0 = wv * HID + hc0; g_arow0 = row0;
    convert(0);
    gbar();
    for (int t = 0; t < TSEQ; ++t) {
        g_Axh = (t & 1) ? x_hi1 : x_hi0;  g_Axl = (t & 1) ? x_lo1 : x_lo0;
        g_Ahh = (t & 1) ? h_hi1 : h_hi0;  g_Ahl = (t & 1) ? h_lo1 : h_lo0;
        unsigned short* Ohh = (t & 1) ? h_hi0 : h_hi1;
        unsigned short* Ohl = (t & 1) ? h_lo0 : h_lo1;
        f32x4 acc[2][2];
        { f32x4 z; z[0]=0.f;z[1]=0.f;z[2]=0.f;z[3]=0.f;
          acc[0][0]=z;acc[0][1]=z;acc[1][0]=z;acc[1][1]=z; }
        run_chunks(24, acc);
        acc2sG(acc);
        __syncthreads();
        #pragma unroll
        for (int q = 0; q < 4; ++q) {
            const int m = mq + (q << 4);
            const int grow = row0 + m;
            const float gi = sG[n][m] + be0;
            const float gf = sG[16 + n][m] + be1;
            const float go = sG[32 + n][m] + be2;
            const float gg = sG[48 + n][m] + be3;
            const float si = fsig(gi), sf = fsig(gf), so = fsig(go);
            const float tg = ftanh(gg);
            const size_t ci = (size_t)grow * HID + hc0 + n;
            const float cnew = sf * c0[ci] + si * tg;   // c0: WG-private, plain
            c0[ci] = cnew;
            const float hnew = so * ftanh(cnew);
            const unsigned short hh = f2bf(hnew);
            st16_ag(Ohh + ci, hh);
            st16_ag(Ohl + ci, f2bf(hnew - bf2f(hh)));
            if (t == TSEQ - 1) {
                const unsigned short ch = f2bf(cnew);
                st16_ag(ce_hi + ci, ch);
                st16_ag(ce_lo + ci, f2bf(cnew - bf2f(ch)));
            }
        }
        if (t < TSEQ - 1) convert(t + 1);
        gbar();
    }

    // ============ dec_const: h_enc @ dec_W[0:1024] + dec_b -> 16 regs ============
    float dk[16];
    {
        g_Bh = decT_hi; g_Bl = decT_lo; g_sb = 2048; g_kb0 = 0; g_nx = 0;
        g_Ahh = h_hi0; g_Ahl = h_lo0;       // h_enc (t=255 wrote buf 0)
        g_colw0 = wv * HID + hc0; g_arow0 = row0;
        f32x4 acc[2][2];
        { f32x4 z; z[0]=0.f;z[1]=0.f;z[2]=0.f;z[3]=0.f;
          acc[0][0]=z;acc[0][1]=z;acc[1][0]=z;acc[1][1]=z; }
        run_chunks(16, acc);
        acc2sG(acc);
        __syncthreads();
        #pragma unroll
        for (int q = 0; q < 4; ++q) {
            const int m = mq + (q << 4);
            dk[q * 4 + 0] = sG[n][m]      + dec_b[hc0 + n];
            dk[q * 4 + 1] = sG[16 + n][m] + dec_b[HID + hc0 + n];
            dk[q * 4 + 2] = sG[32 + n][m] + dec_b[2 * HID + hc0 + n];
            dk[q * 4 + 3] = sG[48 + n][m] + dec_b[3 * HID + hc0 + n];
        }
        gbar();
    }

    // ============ projections: h_cur = h_enc@Wh+bh ; c_cur = c_enc@Wc+bc ============
    if (wg < 128) {
        const int isWc = wg >> 6;
        const int wgl  = wg & 63;
        const int mgp = wgl >> 4, ngp = wgl & 15;
        g_arow0 = mgp << 6;
        g_colw0 = (ngp << 6) + (wv << 4);
        g_Bh = isWc ? WcT_hi : WhT_hi;  g_Bl = isWc ? WcT_lo : WhT_lo;
        g_sb = 1024; g_kb0 = 0; g_nx = 0;
        g_Ahh = isWc ? ce_hi : h_hi0;   g_Ahl = isWc ? ce_lo : h_lo0;
        f32x4 acc[2][2];
        { f32x4 z; z[0]=0.f;z[1]=0.f;z[2]=0.f;z[3]=0.f;
          acc[0][0]=z;acc[0][1]=z;acc[1][0]=z;acc[1][1]=z; }
        run_chunks(16, acc);
        #pragma unroll
        for (int ms = 0; ms < 2; ++ms)
            #pragma unroll
            for (int ns = 0; ns < 2; ++ns)
                #pragma unroll
                for (int r = 0; r < 4; ++r) {
                    const int rowp = (mgp << 6) + rA + (ms << 4) + ((lane >> 4) << 2) + r;
                    const int colp = (ngp << 6) + cB + (ns << 4) + (lane & 15);
                    const size_t o = (size_t)rowp * HID + colp;
                    if (isWc) {
                        st32_ag((unsigned*)(c1 + o),
                                __float_as_uint(acc[ms][ns][r] + bcv[colp]));
                    } else {
                        const float v = acc[ms][ns][r] + bhv[colp];
                        const unsigned short hh = f2bf(v);
                        st16_ag(h_hi1 + o, hh);
                        st16_ag(h_lo1 + o, f2bf(v - bf2f(hh)));
                    }
                }
    }
    gbar();

    // ================= decoder: 256 steps =================
    g_Bh = decT_hi; g_Bl = decT_lo; g_sb = 2048; g_kb0 = 1024; g_nx = 0;
    g_colw0 = wv * HID + hc0; g_arow0 = row0;
    // c-state -> registers; init from proj output (cross-WG -> agent loads),
    // then force-drain so run_chunks' vmcnt ladder starts clean.
    float creg[4];
    #pragma unroll
    for (int q = 0; q < 4; ++q) {
        const size_t ci = (size_t)(row0 + mq + (q << 4)) * HID + hc0 + n;
        creg[q] = __uint_as_float(__hip_atomic_load((const unsigned*)(c1 + ci),
                      __ATOMIC_RELAXED, __HIP_MEMORY_SCOPE_AGENT));
    }
    asm volatile("s_waitcnt vmcnt(0)" ::: "memory");
    for (int t = 0; t < TSEQ; ++t) {
        g_Ahh = (t & 1) ? h_hi0 : h_hi1;  g_Ahl = (t & 1) ? h_lo0 : h_lo1;
        unsigned short* Ohh = (t & 1) ? h_hi1 : h_hi0;
        unsigned short* Ohl = (t & 1) ? h_lo1 : h_lo0;
        f32x4 acc[2][2];
        { f32x4 z; z[0]=0.f;z[1]=0.f;z[2]=0.f;z[3]=0.f;
          acc[0][0]=z;acc[0][1]=z;acc[1][0]=z;acc[1][1]=z; }
        run_chunks(16, acc);
        acc2sG(acc);
        __syncthreads();
        #pragma unroll
        for (int q = 0; q < 4; ++q) {
            const int m = mq + (q << 4);
            const int grow = row0 + m;
            const float gi = sG[n][m]      + dk[q * 4 + 0];
            const float gf = sG[16 + n][m] + dk[q * 4 + 1];
            const float go = sG[32 + n][m] + dk[q * 4 + 2];
            const float gg = sG[48 + n][m] + dk[q * 4 + 3];
            const float si = fsig(gi), sf = fsig(gf), so = fsig(go);
            const float tg = ftanh(gg);
            const float cnew = sf * creg[q] + si * tg;
            creg[q] = cnew;
            const float hnew = so * ftanh(cnew);
            const size_t ci = (size_t)grow * HID + hc0 + n;
            const unsigned short hh = f2bf(hnew);
            st16_ag(Ohh + ci, hh);
            st16_ag(Ohl + ci, f2bf(hnew - bf2f(hh)));
            __builtin_nontemporal_store(hnew,
                out + ((size_t)grow * TSEQ + t) * HID + hc0 + n);
        }
        if (t < TSEQ - 1) gbar();
    }
}

extern "C" void kernel_launch(void* const* d_in, const int* in_sizes, int n_in,
                              void* d_out, int out_size, void* d_ws, size_t ws_size,
                              hipStream_t stream) {
    (void)in_sizes; (void)n_in; (void)out_size;
    const float* x     = (const float*)d_in[0];
    const float* enc_W = (const float*)d_in[1];
    const float* enc_b = (const float*)d_in[2];
    const float* dec_W = (const float*)d_in[3];
    const float* dec_b = (const float*)d_in[4];
    const float* Wh    = (const float*)d_in[5];
    const float* bh    = (const float*)d_in[6];
    const float* Wc    = (const float*)d_in[7];
    const float* bc    = (const float*)d_in[8];
    float* out = (float*)d_out;

    char* w = (char*)d_ws;
    size_t off = 0;
    auto alloc = [&](size_t bytes) -> void* {
        off = (off + 255) & ~(size_t)255;
        void* p = w + off;
        off += bytes;
        return p;
    };
    unsigned short* encT_hi = (unsigned short*)alloc((size_t)G4 * 1536 * 2);
    unsigned short* encT_lo = (unsigned short*)alloc((size_t)G4 * 1536 * 2);
    unsigned short* decT_hi = (unsigned short*)alloc((size_t)G4 * 2048 * 2);
    unsigned short* decT_lo = (unsigned short*)alloc((size_t)G4 * 2048 * 2);
    unsigned short* WhT_hi  = (unsigned short*)alloc((size_t)HID * HID * 2);
    unsigned short* WhT_lo  = (unsigned short*)alloc((size_t)HID * HID * 2);
    unsigned short* WcT_hi  = (unsigned short*)alloc((size_t)HID * HID * 2);
    unsigned short* WcT_lo  = (unsigned short*)alloc((size_t)HID * HID * 2);
    unsigned short* h_hi0 = (unsigned short*)alloc((size_t)NB * HID * 2);
    unsigned short* h_lo0 = (unsigned short*)alloc((size_t)NB * HID * 2);
    unsigned short* h_hi1 = (unsigned short*)alloc((size_t)NB * HID * 2);
    unsigned short* h_lo1 = (unsigned short*)alloc((size_t)NB * HID * 2);
    unsigned short* ce_hi = (unsigned short*)alloc((size_t)NB * HID * 2);
    unsigned short* ce_lo = (unsigned short*)alloc((size_t)NB * HID * 2);
    float* c0 = (float*)alloc((size_t)NB * HID * 4);
    float* c1 = (float*)alloc((size_t)NB * HID * 4);
    unsigned short* x_hi0 = (unsigned short*)alloc((size_t)NB * DIN * 2);
    unsigned short* x_lo0 = (unsigned short*)alloc((size_t)NB * DIN * 2);
    unsigned short* x_hi1 = (unsigned short*)alloc((size_t)NB * DIN * 2);
    unsigned short* x_lo1 = (unsigned short*)alloc((size_t)NB * DIN * 2);
    unsigned* barcnt = (unsigned*)alloc(2048);
    if (off > ws_size) return;  // ~74MB required

    split_transpose<<<dim3(1536 / 64, G4 / 64), 256, 0, stream>>>(enc_W, encT_hi, encT_lo, 1536, G4);
    split_transpose<<<dim3(2048 / 64, G4 / 64), 256, 0, stream>>>(dec_W, decT_hi, decT_lo, 2048, G4);
    split_transpose<<<dim3(HID / 64, HID / 64), 256, 0, stream>>>(Wh, WhT_hi, WhT_lo, HID, HID);
    split_transpose<<<dim3(HID / 64, HID / 64), 256, 0, stream>>>(Wc, WcT_hi, WcT_lo, HID, HID);
    (void)hipMemsetAsync(h_hi0, 0, (size_t)NB * HID * 2, stream);
    (void)hipMemsetAsync(h_lo0, 0, (size_t)NB * HID * 2, stream);
    (void)hipMemsetAsync(c0,    0, (size_t)NB * HID * 4, stream);
    (void)hipMemsetAsync(barcnt, 0, 2048, stream);

    lstm_persist<<<256, 256, 0, stream>>>(
        x, encT_hi, encT_lo, decT_hi, decT_lo, WhT_hi, WhT_lo, WcT_hi, WcT_lo,
        enc_b, dec_b, bh, bc,
        h_hi0, h_lo0, h_hi1, h_lo1, ce_hi, ce_lo, c0, c1,
        x_hi0, x_lo0, x_hi1, x_lo1, barcnt, out);
}